// Round 17
// baseline (2822.907 us; speedup 1.0000x reference)
//
#include <hip/hip_runtime.h>
#include <math.h>

// ESN: 512 sequential steps of h = tanh([h | x_t] @ [W_hh|W_ih]^T + b)
// T=512, B=64, I=128, H=1024, K' = 1152.
//
// R21 (from R18 @ 2.55 ms; R19/R20's register-async prefetch was unsound --
// asm loads are invisible to hipcc's waitcnt pass and nothing ties the
// poison check to them): LDS-DMA prefetch of the sentinel-guarded h data.
//  * __builtin_amdgcn_global_load_lds (compiler-modeled, vmcnt-tracked)
//    DMAs each chain's h chunks directly into its wave-private LDS staging
//    buffer, issued ONE PHASE EARLY (B's data during phase A; A's next-step
//    data during phase B). Fetch RT hides under the other chain's FMA.
//  * Sound ordering: consume = s_waitcnt vmcnt(0) asm ("memory" clobber)
//    -> ds_read -> poison check. ds_read is a MEMORY op: it cannot cross
//    the clobbered asm (unlike R20's register-only checks). syncthreads
//    additionally drains the compiler-known DMA.
//  * Fail-safe: every out location is written exactly once, so any stale
//    or misconfigured read yields POISON -> R18's proven direct sc-load
//    retry overwrites LDS. Worst case = R18 perf, never wrong data.
//  * DMA dest layout: staging chunk is base + lane*16B exactly (HW
//    semantics: wave-uniform base + lane*size). aux=17 = SC0|SC1.
//  * Everything else = R18 (proven): two independent 4-row chains per WG
//    interleaved, sentinel sync (out pre-poisoned 0x7F7F7F7F, data IS the
//    flag, fire-and-forget sc0sc1 16B stores), one syncthreads per phase,
//    W (18 float4) + bias VGPR-resident, x prefetch.

#define T_STEPS 512
#define BATCH   64
#define HDIM    1024
#define IDIM    128
#define KDIM    1152
#define NWG     256
#define NB      4
#define POISON  0x7F7F7F7Fu

typedef float f32x4_t __attribute__((ext_vector_type(4)));
typedef __attribute__((address_space(3))) void lds_void;
typedef __attribute__((address_space(1))) const void gm_void;

// async global->LDS DMA, 16B/lane, coherence-point read (SC0|SC1 = 1|16)
__device__ __forceinline__ void issue_dma16(const float* g, float* l) {
    __builtin_amdgcn_global_load_lds((gm_void*)g, (lds_void*)l, 16, 0, 17);
}

// wait all outstanding vmem (covers the DMAs); "memory" clobber orders all
// following MEMORY ops (the ds_read checks) after it.
__device__ __forceinline__ void wait_vmem0(void) {
    asm volatile("s_waitcnt vmcnt(0)" ::: "memory");
}

// 2 x 16B coherence-point loads + blocking drain (retry path, R12-proven).
__device__ __forceinline__ void sc_load2x4(const float* p0, const float* p1,
                                           float4& a, float4& b) {
    asm volatile(
        "global_load_dwordx4 %0, %2, off sc0 sc1\n\t"
        "global_load_dwordx4 %1, %3, off sc0 sc1\n\t"
        "s_waitcnt vmcnt(0)"
        : "=&v"(a), "=&v"(b)
        : "v"(p0), "v"(p1)
        : "memory");
}

// 16B write-through store (no drain: visibility rides the write)
__device__ __forceinline__ void sc_store4_nodrain(float* p, float4 v) {
    f32x4_t t;
    t.x = v.x; t.y = v.y; t.z = v.z; t.w = v.w;
    asm volatile("global_store_dwordx4 %0, %1, off sc0 sc1"
                 :: "v"(p), "v"(t) : "memory");
}

__device__ __forceinline__ unsigned chk4(float4 v) {
    return (unsigned)((__float_as_uint(v.x) == POISON) |
                      (__float_as_uint(v.y) == POISON) |
                      (__float_as_uint(v.z) == POISON) |
                      (__float_as_uint(v.w) == POISON));
}

// src[R][C] -> dst[C][R], 64x64 LDS tiles, grid = (C/64)*(R/64), 256 thr
__global__ void transpose_f32(const float* __restrict__ src, float* __restrict__ dst,
                              int R, int C) {
    __shared__ float tile[64][65];
    const int tcol = threadIdx.x & 63;
    const int trow = threadIdx.x >> 6;
    const int nbx = C >> 6;
    const int bx = blockIdx.x % nbx;
    const int by = blockIdx.x / nbx;
    const int c0 = bx << 6, r0 = by << 6;
    for (int i = trow; i < 64; i += 4)
        tile[i][tcol] = src[(size_t)(r0 + i) * C + c0 + tcol];
    __syncthreads();
    for (int i = trow; i < 64; i += 4)
        dst[(size_t)(c0 + i) * R + r0 + tcol] = tile[tcol][i];
}

__global__ __launch_bounds__(512) void esn_persistent(
    const float* __restrict__ x,     // [512][64][128]
    const float* __restrict__ h0,    // [64][1024]
    const float* __restrict__ WT,    // [1152][1024]
    const float* __restrict__ bias,  // [1024]
    float* __restrict__ out,         // [512][64][1024] (pre-poisoned)
    float* __restrict__ hfin)        // [64][1024]
{
    const int tid  = threadIdx.x;
    const int wg   = blockIdx.x;
    const int wave = tid >> 6;                       // 0..7 (k-slice; 0-3 epi row)
    const int lane = tid & 63;
    const int jq   = lane & 7;                       // 4 j each -> 32 j
    const int ksub = lane >> 3;                      // 0..7 k-interleave
    const int jblk = ((wg & 7) << 2) | ((wg >> 3) & 3);  // XCD owns 4 jblks
    const int bgrp = wg >> 5;                            // 0..7
    const int b0   = bgrp << 3;                          // 8 rows: A=0..3, B=4..7
    const int j0   = (jblk << 5) + (jq << 2);
    const int krec = wave << 7;                      // recurrent k base (128/wave)
    const int kx   = HDIM + (wave << 4) + (ksub << 1);  // x-part rows (2 each)

    // chain-private staging blocks
    __shared__ float  htA[8 * 512];                  // [wave][4 rows][128 k] 16KB
    __shared__ float  htB[8 * 512];                  // 16KB
    __shared__ float  hxA[8 * 64];                   // [wave][4 rows][16 xk]  2KB
    __shared__ float  hxB[8 * 64];                   //  2KB
    __shared__ float4 redA[8 * 8 * 5];               // [w][jq] stride 5       5KB
    __shared__ float4 redB[8 * 8 * 5];               //  5KB

    // ---- hoist all 18 W float4 loads for ALL 512 steps (72 VGPRs) ----
    float4 Wv[18];
    {
        const float* wp = WT + (size_t)krec * HDIM + j0;
        #pragma unroll
        for (int i = 0; i < 4; ++i) {
            const int kk = ((i << 3) + ksub) << 2;      // 0..124 step 4
            const float* wk = wp + (size_t)kk * HDIM;
            Wv[i * 4 + 0] = *(const float4*)(wk);
            Wv[i * 4 + 1] = *(const float4*)(wk + HDIM);
            Wv[i * 4 + 2] = *(const float4*)(wk + 2 * HDIM);
            Wv[i * 4 + 3] = *(const float4*)(wk + 3 * HDIM);
        }
        const float* wkx = WT + (size_t)kx * HDIM + j0;
        Wv[16] = *(const float4*)(wkx);
        Wv[17] = *(const float4*)(wkx + HDIM);
    }

    // ---- epilogue constants: waves 0-3 lanes 0-7 handle one row/chain ----
    float4 b4 = make_float4(0.f, 0.f, 0.f, 0.f);
    int jj = 0;
    if (lane < 8) {
        jj = (jblk << 5) + (lane << 2);
        b4 = *(const float4*)(bias + jj);
    }

    // ---- staging lane maps (4 rows/chain: lane covers rows sbb, sbb+2) ----
    const int sbb = lane >> 5;                 // row parity (0/1)
    const int sko = (lane & 31) << 2;          // k-offset within slice
    float* hdA = htA + (wave << 9) + (sbb << 7) + sko;   // == base + lane*16B
    float* hdB = htB + (wave << 9) + (sbb << 7) + sko;
    const int xr = lane >> 4;                  // x row 0..3
    const int xco = lane & 15;                 // x col within 16-slice
    float* xdA = hxA + (wave << 6) + (xr << 4) + xco;
    float* xdB = hxB + (wave << 6) + (xr << 4) + xco;
    const float* hbA = htA + (wave << 9);
    const float* hbB = htB + (wave << 9);
    const float* xbA = hxA + (wave << 6);
    const float* xbB = hxB + (wave << 6);

    // ---- prefetch x slices for t=0 (plain cached loads, x read-only) ----
    float xvA = x[(size_t)(b0 + xr) * IDIM + (wave << 4) + xco];
    float xvB = x[(size_t)(b0 + 4 + xr) * IDIM + (wave << 4) + xco];

    for (int t = 0; t < T_STEPS; ++t) {
        // ================= chain A (rows b0..b0+3) =================
        *xdA = xvA;
        if (t == 0) {
            const float* p = h0 + (size_t)(b0 + sbb) * HDIM + krec + sko;
            *(float4*)(hdA)       = *(const float4*)(p);
            *(float4*)(hdA + 256) = *(const float4*)(p + 2 * HDIM);
        } else {
            // A's data was DMA'd into htA during phase B(t-1); DMA drained
            // by the intervening syncthreads + this vmcnt(0). ds_read is a
            // memory op -> cannot be reordered above the clobbered asm.
            wait_vmem0();
            float4 a = *(const float4*)(hdA);
            float4 b = *(const float4*)(hdA + 256);
            if (__any((int)(chk4(a) | chk4(b)))) {
                const float* p = out + ((size_t)(t - 1) * BATCH + b0 + sbb) * HDIM
                                 + krec + sko;
                do { sc_load2x4(p, p + 2 * HDIM, a, b); }
                while (__any((int)(chk4(a) | chk4(b))));
                *(float4*)(hdA)       = a;
                *(float4*)(hdA + 256) = b;
            }
        }
        // issue chain B's step-t DMA (RT hides under FMA_A; drained @syncA)
        if (t > 0) {
            const float* pB = out + ((size_t)(t - 1) * BATCH + b0 + 4 + sbb) * HDIM
                              + krec + sko;
            issue_dma16(pB, hdB);
            issue_dma16(pB + 2 * HDIM, hdB + 256);
        }
        if (t + 1 < T_STEPS)
            xvA = x[((size_t)(t + 1) * BATCH + b0 + xr) * IDIM + (wave << 4) + xco];

        {
            float4 acc[NB];
            #pragma unroll
            for (int bb = 0; bb < NB; ++bb) acc[bb] = make_float4(0.f, 0.f, 0.f, 0.f);
            #pragma unroll
            for (int i = 0; i < 4; ++i) {
                const int ko = ((i << 3) + ksub) << 2;
                const float4 w0 = Wv[i * 4 + 0], w1 = Wv[i * 4 + 1];
                const float4 w2 = Wv[i * 4 + 2], w3 = Wv[i * 4 + 3];
                #pragma unroll
                for (int bb = 0; bb < NB; ++bb) {
                    float4 h4 = *(const float4*)(hbA + (bb << 7) + ko);
                    acc[bb].x = fmaf(w0.x, h4.x, acc[bb].x);
                    acc[bb].y = fmaf(w0.y, h4.x, acc[bb].y);
                    acc[bb].z = fmaf(w0.z, h4.x, acc[bb].z);
                    acc[bb].w = fmaf(w0.w, h4.x, acc[bb].w);
                    acc[bb].x = fmaf(w1.x, h4.y, acc[bb].x);
                    acc[bb].y = fmaf(w1.y, h4.y, acc[bb].y);
                    acc[bb].z = fmaf(w1.z, h4.y, acc[bb].z);
                    acc[bb].w = fmaf(w1.w, h4.y, acc[bb].w);
                    acc[bb].x = fmaf(w2.x, h4.z, acc[bb].x);
                    acc[bb].y = fmaf(w2.y, h4.z, acc[bb].y);
                    acc[bb].z = fmaf(w2.z, h4.z, acc[bb].z);
                    acc[bb].w = fmaf(w2.w, h4.z, acc[bb].w);
                    acc[bb].x = fmaf(w3.x, h4.w, acc[bb].x);
                    acc[bb].y = fmaf(w3.y, h4.w, acc[bb].y);
                    acc[bb].z = fmaf(w3.z, h4.w, acc[bb].z);
                    acc[bb].w = fmaf(w3.w, h4.w, acc[bb].w);
                }
            }
            #pragma unroll
            for (int bb = 0; bb < NB; ++bb) {
                float2 hx = *(const float2*)(xbA + (bb << 4) + (ksub << 1));
                acc[bb].x = fmaf(Wv[16].x, hx.x, acc[bb].x);
                acc[bb].y = fmaf(Wv[16].y, hx.x, acc[bb].y);
                acc[bb].z = fmaf(Wv[16].z, hx.x, acc[bb].z);
                acc[bb].w = fmaf(Wv[16].w, hx.x, acc[bb].w);
                acc[bb].x = fmaf(Wv[17].x, hx.y, acc[bb].x);
                acc[bb].y = fmaf(Wv[17].y, hx.y, acc[bb].y);
                acc[bb].z = fmaf(Wv[17].z, hx.y, acc[bb].z);
                acc[bb].w = fmaf(Wv[17].w, hx.y, acc[bb].w);
            }
            #pragma unroll
            for (int bb = 0; bb < NB; ++bb) {
                acc[bb].x += __shfl_xor(acc[bb].x, 8);
                acc[bb].y += __shfl_xor(acc[bb].y, 8);
                acc[bb].z += __shfl_xor(acc[bb].z, 8);
                acc[bb].w += __shfl_xor(acc[bb].w, 8);
                acc[bb].x += __shfl_xor(acc[bb].x, 16);
                acc[bb].y += __shfl_xor(acc[bb].y, 16);
                acc[bb].z += __shfl_xor(acc[bb].z, 16);
                acc[bb].w += __shfl_xor(acc[bb].w, 16);
                acc[bb].x += __shfl_xor(acc[bb].x, 32);
                acc[bb].y += __shfl_xor(acc[bb].y, 32);
                acc[bb].z += __shfl_xor(acc[bb].z, 32);
                acc[bb].w += __shfl_xor(acc[bb].w, 32);
            }
            if (ksub == 0) {
                #pragma unroll
                for (int bb = 0; bb < NB; ++bb)
                    redA[((wave << 3) + jq) * 5 + bb] = acc[bb];
            }
        }
        __syncthreads();                               // redA(t) + B-DMA drain
        if (wave < 4 && lane < 8) {
            float4 s = make_float4(0.f, 0.f, 0.f, 0.f);
            #pragma unroll
            for (int w = 0; w < 8; ++w) {
                float4 r = redA[((w << 3) + lane) * 5 + wave];
                s.x += r.x; s.y += r.y; s.z += r.z; s.w += r.w;
            }
            float4 o;
            o.x = tanhf(s.x + b4.x);
            o.y = tanhf(s.y + b4.y);
            o.z = tanhf(s.z + b4.z);
            o.w = tanhf(s.w + b4.w);
            sc_store4_nodrain(out + ((size_t)t * BATCH + b0 + wave) * HDIM + jj, o);
            if (t == T_STEPS - 1)
                *(float4*)(hfin + (size_t)(b0 + wave) * HDIM + jj) = o;
        }

        // ================= chain B (rows b0+4..b0+7) =================
        *xdB = xvB;
        if (t == 0) {
            const float* p = h0 + (size_t)(b0 + 4 + sbb) * HDIM + krec + sko;
            *(float4*)(hdB)       = *(const float4*)(p);
            *(float4*)(hdB + 256) = *(const float4*)(p + 2 * HDIM);
        } else {
            wait_vmem0();
            float4 a = *(const float4*)(hdB);
            float4 b = *(const float4*)(hdB + 256);
            if (__any((int)(chk4(a) | chk4(b)))) {
                const float* p = out + ((size_t)(t - 1) * BATCH + b0 + 4 + sbb) * HDIM
                                 + krec + sko;
                do { sc_load2x4(p, p + 2 * HDIM, a, b); }
                while (__any((int)(chk4(a) | chk4(b))));
                *(float4*)(hdB)       = a;
                *(float4*)(hdB + 256) = b;
            }
        }
        // issue chain A's step-(t+1) DMA (A(t) just published by us; RT +
        // skew hides under FMA_B; drained @syncB)
        if (t + 1 < T_STEPS) {
            const float* pA = out + ((size_t)t * BATCH + b0 + sbb) * HDIM
                              + krec + sko;
            issue_dma16(pA, hdA);
            issue_dma16(pA + 2 * HDIM, hdA + 256);
        }
        if (t + 1 < T_STEPS)
            xvB = x[((size_t)(t + 1) * BATCH + b0 + 4 + xr) * IDIM
                    + (wave << 4) + xco];

        {
            float4 acc[NB];
            #pragma unroll
            for (int bb = 0; bb < NB; ++bb) acc[bb] = make_float4(0.f, 0.f, 0.f, 0.f);
            #pragma unroll
            for (int i = 0; i < 4; ++i) {
                const int ko = ((i << 3) + ksub) << 2;
                const float4 w0 = Wv[i * 4 + 0], w1 = Wv[i * 4 + 1];
                const float4 w2 = Wv[i * 4 + 2], w3 = Wv[i * 4 + 3];
                #pragma unroll
                for (int bb = 0; bb < NB; ++bb) {
                    float4 h4 = *(const float4*)(hbB + (bb << 7) + ko);
                    acc[bb].x = fmaf(w0.x, h4.x, acc[bb].x);
                    acc[bb].y = fmaf(w0.y, h4.x, acc[bb].y);
                    acc[bb].z = fmaf(w0.z, h4.x, acc[bb].z);
                    acc[bb].w = fmaf(w0.w, h4.x, acc[bb].w);
                    acc[bb].x = fmaf(w1.x, h4.y, acc[bb].x);
                    acc[bb].y = fmaf(w1.y, h4.y, acc[bb].y);
                    acc[bb].z = fmaf(w1.z, h4.y, acc[bb].z);
                    acc[bb].w = fmaf(w1.w, h4.y, acc[bb].w);
                    acc[bb].x = fmaf(w2.x, h4.z, acc[bb].x);
                    acc[bb].y = fmaf(w2.y, h4.z, acc[bb].y);
                    acc[bb].z = fmaf(w2.z, h4.z, acc[bb].z);
                    acc[bb].w = fmaf(w2.w, h4.z, acc[bb].w);
                    acc[bb].x = fmaf(w3.x, h4.w, acc[bb].x);
                    acc[bb].y = fmaf(w3.y, h4.w, acc[bb].y);
                    acc[bb].z = fmaf(w3.z, h4.w, acc[bb].z);
                    acc[bb].w = fmaf(w3.w, h4.w, acc[bb].w);
                }
            }
            #pragma unroll
            for (int bb = 0; bb < NB; ++bb) {
                float2 hx = *(const float2*)(xbB + (bb << 4) + (ksub << 1));
                acc[bb].x = fmaf(Wv[16].x, hx.x, acc[bb].x);
                acc[bb].y = fmaf(Wv[16].y, hx.x, acc[bb].y);
                acc[bb].z = fmaf(Wv[16].z, hx.x, acc[bb].z);
                acc[bb].w = fmaf(Wv[16].w, hx.x, acc[bb].w);
                acc[bb].x = fmaf(Wv[17].x, hx.y, acc[bb].x);
                acc[bb].y = fmaf(Wv[17].y, hx.y, acc[bb].y);
                acc[bb].z = fmaf(Wv[17].z, hx.y, acc[bb].z);
                acc[bb].w = fmaf(Wv[17].w, hx.y, acc[bb].w);
            }
            #pragma unroll
            for (int bb = 0; bb < NB; ++bb) {
                acc[bb].x += __shfl_xor(acc[bb].x, 8);
                acc[bb].y += __shfl_xor(acc[bb].y, 8);
                acc[bb].z += __shfl_xor(acc[bb].z, 8);
                acc[bb].w += __shfl_xor(acc[bb].w, 8);
                acc[bb].x += __shfl_xor(acc[bb].x, 16);
                acc[bb].y += __shfl_xor(acc[bb].y, 16);
                acc[bb].z += __shfl_xor(acc[bb].z, 16);
                acc[bb].w += __shfl_xor(acc[bb].w, 16);
                acc[bb].x += __shfl_xor(acc[bb].x, 32);
                acc[bb].y += __shfl_xor(acc[bb].y, 32);
                acc[bb].z += __shfl_xor(acc[bb].z, 32);
                acc[bb].w += __shfl_xor(acc[bb].w, 32);
            }
            if (ksub == 0) {
                #pragma unroll
                for (int bb = 0; bb < NB; ++bb)
                    redB[((wave << 3) + jq) * 5 + bb] = acc[bb];
            }
        }
        __syncthreads();                               // redB(t) + A-DMA drain
        if (wave < 4 && lane < 8) {
            float4 s = make_float4(0.f, 0.f, 0.f, 0.f);
            #pragma unroll
            for (int w = 0; w < 8; ++w) {
                float4 r = redB[((w << 3) + lane) * 5 + wave];
                s.x += r.x; s.y += r.y; s.z += r.z; s.w += r.w;
            }
            float4 o;
            o.x = tanhf(s.x + b4.x);
            o.y = tanhf(s.y + b4.y);
            o.z = tanhf(s.z + b4.z);
            o.w = tanhf(s.w + b4.w);
            sc_store4_nodrain(out + ((size_t)t * BATCH + b0 + 4 + wave) * HDIM + jj, o);
            if (t == T_STEPS - 1)
                *(float4*)(hfin + (size_t)(b0 + 4 + wave) * HDIM + jj) = o;
        }
    }
}

extern "C" void kernel_launch(void* const* d_in, const int* in_sizes, int n_in,
                              void* d_out, int out_size, void* d_ws, size_t ws_size,
                              hipStream_t stream) {
    const float* x    = (const float*)d_in[0];
    const float* h0   = (const float*)d_in[1];
    const float* w_ih = (const float*)d_in[2];   // [1024][128]
    const float* w_hh = (const float*)d_in[3];   // [1024][1024]
    const float* bias = (const float*)d_in[4];   // [1024]
    float* out = (float*)d_out;

    char* ws = (char*)d_ws;
    float* WT = (float*)ws;                      // [1152][1024] = 4.72 MB

    // poison the polled region: byte 0x7F -> dword 0x7F7F7F7F = 3.4e38,
    // unreachable by tanh. Stream-ordered; re-arms on every replay.
    (void)hipMemsetAsync(out, 0x7F,
                         (size_t)T_STEPS * BATCH * HDIM * sizeof(float), stream);
    transpose_f32<<<256, 256, 0, stream>>>(w_hh, WT, HDIM, HDIM);
    transpose_f32<<<32, 256, 0, stream>>>(w_ih, WT + (size_t)HDIM * HDIM, HDIM, IDIM);
    esn_persistent<<<NWG, 512, 0, stream>>>(x, h0, WT, bias,
                                            out, out + (size_t)T_STEPS * BATCH * HDIM);
}

// Round 18
// 2659.669 us; speedup vs baseline: 1.0614x; 1.0614x over previous
//
#include <hip/hip_runtime.h>
#include <math.h>

// ESN: 512 sequential steps of h = tanh([h | x_t] @ [W_hh|W_ih]^T + b)
// T=512, B=64, I=128, H=1024, K' = 1152.
//
// R22 (from R21 @ 2.82 ms, R18 @ 2.55 ms): R21's LDS-DMA prefetch with the
// issue points moved LATE (after the other chain's sync, before its epi).
//  * R21's regression signature: FETCH 600->800 MB = ~1/3 of prefetches hit
//    poison (issued ~0.2-0.7us after publish < delta) and were retried --
//    prefetch traffic + full blocking retry. R22 issues B's step-t DMA
//    after syncA (publisher aged ~2.5us) and A's step-(t+1) DMA after
//    syncB (aged ~2us): both past delta, so prefetches return real data;
//    flight overlaps epi + next phase entry.
//  * Mechanism unchanged (R21-proven correct): __builtin_amdgcn_global_load_lds
//    (compiler-modeled, vmcnt-tracked) into wave-private LDS staging;
//    consume = s_waitcnt vmcnt(0) asm ("memory") -> ds_read -> poison check
//    (memory-op ordered, sound); retry fallback = R12's blocking sc-loads.
//  * Everything else = R18: two independent 4-row chains per WG interleaved,
//    sentinel sync (out pre-poisoned 0x7F7F7F7F, data IS the flag,
//    fire-and-forget sc0sc1 16B stores), W (18 float4) + bias VGPR-resident,
//    x prefetch.

#define T_STEPS 512
#define BATCH   64
#define HDIM    1024
#define IDIM    128
#define KDIM    1152
#define NWG     256
#define NB      4
#define POISON  0x7F7F7F7Fu

typedef float f32x4_t __attribute__((ext_vector_type(4)));
typedef __attribute__((address_space(3))) void lds_void;
typedef __attribute__((address_space(1))) const void gm_void;

// async global->LDS DMA, 16B/lane, coherence-point read (SC0|SC1 = 1|16)
__device__ __forceinline__ void issue_dma16(const float* g, float* l) {
    __builtin_amdgcn_global_load_lds((gm_void*)g, (lds_void*)l, 16, 0, 17);
}

// wait all outstanding vmem (covers the DMAs); "memory" clobber orders all
// following MEMORY ops (the ds_read checks) after it.
__device__ __forceinline__ void wait_vmem0(void) {
    asm volatile("s_waitcnt vmcnt(0)" ::: "memory");
}

// 2 x 16B coherence-point loads + blocking drain (retry path, R12-proven).
__device__ __forceinline__ void sc_load2x4(const float* p0, const float* p1,
                                           float4& a, float4& b) {
    asm volatile(
        "global_load_dwordx4 %0, %2, off sc0 sc1\n\t"
        "global_load_dwordx4 %1, %3, off sc0 sc1\n\t"
        "s_waitcnt vmcnt(0)"
        : "=&v"(a), "=&v"(b)
        : "v"(p0), "v"(p1)
        : "memory");
}

// 16B write-through store (no drain: visibility rides the write)
__device__ __forceinline__ void sc_store4_nodrain(float* p, float4 v) {
    f32x4_t t;
    t.x = v.x; t.y = v.y; t.z = v.z; t.w = v.w;
    asm volatile("global_store_dwordx4 %0, %1, off sc0 sc1"
                 :: "v"(p), "v"(t) : "memory");
}

__device__ __forceinline__ unsigned chk4(float4 v) {
    return (unsigned)((__float_as_uint(v.x) == POISON) |
                      (__float_as_uint(v.y) == POISON) |
                      (__float_as_uint(v.z) == POISON) |
                      (__float_as_uint(v.w) == POISON));
}

// src[R][C] -> dst[C][R], 64x64 LDS tiles, grid = (C/64)*(R/64), 256 thr
__global__ void transpose_f32(const float* __restrict__ src, float* __restrict__ dst,
                              int R, int C) {
    __shared__ float tile[64][65];
    const int tcol = threadIdx.x & 63;
    const int trow = threadIdx.x >> 6;
    const int nbx = C >> 6;
    const int bx = blockIdx.x % nbx;
    const int by = blockIdx.x / nbx;
    const int c0 = bx << 6, r0 = by << 6;
    for (int i = trow; i < 64; i += 4)
        tile[i][tcol] = src[(size_t)(r0 + i) * C + c0 + tcol];
    __syncthreads();
    for (int i = trow; i < 64; i += 4)
        dst[(size_t)(c0 + i) * R + r0 + tcol] = tile[tcol][i];
}

__global__ __launch_bounds__(512) void esn_persistent(
    const float* __restrict__ x,     // [512][64][128]
    const float* __restrict__ h0,    // [64][1024]
    const float* __restrict__ WT,    // [1152][1024]
    const float* __restrict__ bias,  // [1024]
    float* __restrict__ out,         // [512][64][1024] (pre-poisoned)
    float* __restrict__ hfin)        // [64][1024]
{
    const int tid  = threadIdx.x;
    const int wg   = blockIdx.x;
    const int wave = tid >> 6;                       // 0..7 (k-slice; 0-3 epi row)
    const int lane = tid & 63;
    const int jq   = lane & 7;                       // 4 j each -> 32 j
    const int ksub = lane >> 3;                      // 0..7 k-interleave
    const int jblk = ((wg & 7) << 2) | ((wg >> 3) & 3);  // XCD owns 4 jblks
    const int bgrp = wg >> 5;                            // 0..7
    const int b0   = bgrp << 3;                          // 8 rows: A=0..3, B=4..7
    const int j0   = (jblk << 5) + (jq << 2);
    const int krec = wave << 7;                      // recurrent k base (128/wave)
    const int kx   = HDIM + (wave << 4) + (ksub << 1);  // x-part rows (2 each)

    // chain-private staging blocks
    __shared__ float  htA[8 * 512];                  // [wave][4 rows][128 k] 16KB
    __shared__ float  htB[8 * 512];                  // 16KB
    __shared__ float  hxA[8 * 64];                   // [wave][4 rows][16 xk]  2KB
    __shared__ float  hxB[8 * 64];                   //  2KB
    __shared__ float4 redA[8 * 8 * 5];               // [w][jq] stride 5       5KB
    __shared__ float4 redB[8 * 8 * 5];               //  5KB

    // ---- hoist all 18 W float4 loads for ALL 512 steps (72 VGPRs) ----
    float4 Wv[18];
    {
        const float* wp = WT + (size_t)krec * HDIM + j0;
        #pragma unroll
        for (int i = 0; i < 4; ++i) {
            const int kk = ((i << 3) + ksub) << 2;      // 0..124 step 4
            const float* wk = wp + (size_t)kk * HDIM;
            Wv[i * 4 + 0] = *(const float4*)(wk);
            Wv[i * 4 + 1] = *(const float4*)(wk + HDIM);
            Wv[i * 4 + 2] = *(const float4*)(wk + 2 * HDIM);
            Wv[i * 4 + 3] = *(const float4*)(wk + 3 * HDIM);
        }
        const float* wkx = WT + (size_t)kx * HDIM + j0;
        Wv[16] = *(const float4*)(wkx);
        Wv[17] = *(const float4*)(wkx + HDIM);
    }

    // ---- epilogue constants: waves 0-3 lanes 0-7 handle one row/chain ----
    float4 b4 = make_float4(0.f, 0.f, 0.f, 0.f);
    int jj = 0;
    if (lane < 8) {
        jj = (jblk << 5) + (lane << 2);
        b4 = *(const float4*)(bias + jj);
    }

    // ---- staging lane maps (4 rows/chain: lane covers rows sbb, sbb+2) ----
    const int sbb = lane >> 5;                 // row parity (0/1)
    const int sko = (lane & 31) << 2;          // k-offset within slice
    float* hdA = htA + (wave << 9) + (sbb << 7) + sko;   // == base + lane*16B
    float* hdB = htB + (wave << 9) + (sbb << 7) + sko;
    const int xr = lane >> 4;                  // x row 0..3
    const int xco = lane & 15;                 // x col within 16-slice
    float* xdA = hxA + (wave << 6) + (xr << 4) + xco;
    float* xdB = hxB + (wave << 6) + (xr << 4) + xco;
    const float* hbA = htA + (wave << 9);
    const float* hbB = htB + (wave << 9);
    const float* xbA = hxA + (wave << 6);
    const float* xbB = hxB + (wave << 6);

    // ---- prefetch x slices for t=0 (plain cached loads, x read-only) ----
    float xvA = x[(size_t)(b0 + xr) * IDIM + (wave << 4) + xco];
    float xvB = x[(size_t)(b0 + 4 + xr) * IDIM + (wave << 4) + xco];

    for (int t = 0; t < T_STEPS; ++t) {
        // ================= chain A (rows b0..b0+3) =================
        *xdA = xvA;
        if (t == 0) {
            const float* p = h0 + (size_t)(b0 + sbb) * HDIM + krec + sko;
            *(float4*)(hdA)       = *(const float4*)(p);
            *(float4*)(hdA + 256) = *(const float4*)(p + 2 * HDIM);
        } else {
            // A's data was DMA'd into htA after syncB(t-1); drained here.
            wait_vmem0();
            float4 a = *(const float4*)(hdA);
            float4 b = *(const float4*)(hdA + 256);
            if (__any((int)(chk4(a) | chk4(b)))) {
                const float* p = out + ((size_t)(t - 1) * BATCH + b0 + sbb) * HDIM
                                 + krec + sko;
                do { sc_load2x4(p, p + 2 * HDIM, a, b); }
                while (__any((int)(chk4(a) | chk4(b))));
                *(float4*)(hdA)       = a;
                *(float4*)(hdA + 256) = b;
            }
        }
        if (t + 1 < T_STEPS)
            xvA = x[((size_t)(t + 1) * BATCH + b0 + xr) * IDIM + (wave << 4) + xco];

        {
            float4 acc[NB];
            #pragma unroll
            for (int bb = 0; bb < NB; ++bb) acc[bb] = make_float4(0.f, 0.f, 0.f, 0.f);
            #pragma unroll
            for (int i = 0; i < 4; ++i) {
                const int ko = ((i << 3) + ksub) << 2;
                const float4 w0 = Wv[i * 4 + 0], w1 = Wv[i * 4 + 1];
                const float4 w2 = Wv[i * 4 + 2], w3 = Wv[i * 4 + 3];
                #pragma unroll
                for (int bb = 0; bb < NB; ++bb) {
                    float4 h4 = *(const float4*)(hbA + (bb << 7) + ko);
                    acc[bb].x = fmaf(w0.x, h4.x, acc[bb].x);
                    acc[bb].y = fmaf(w0.y, h4.x, acc[bb].y);
                    acc[bb].z = fmaf(w0.z, h4.x, acc[bb].z);
                    acc[bb].w = fmaf(w0.w, h4.x, acc[bb].w);
                    acc[bb].x = fmaf(w1.x, h4.y, acc[bb].x);
                    acc[bb].y = fmaf(w1.y, h4.y, acc[bb].y);
                    acc[bb].z = fmaf(w1.z, h4.y, acc[bb].z);
                    acc[bb].w = fmaf(w1.w, h4.y, acc[bb].w);
                    acc[bb].x = fmaf(w2.x, h4.z, acc[bb].x);
                    acc[bb].y = fmaf(w2.y, h4.z, acc[bb].y);
                    acc[bb].z = fmaf(w2.z, h4.z, acc[bb].z);
                    acc[bb].w = fmaf(w2.w, h4.z, acc[bb].w);
                    acc[bb].x = fmaf(w3.x, h4.w, acc[bb].x);
                    acc[bb].y = fmaf(w3.y, h4.w, acc[bb].y);
                    acc[bb].z = fmaf(w3.z, h4.w, acc[bb].z);
                    acc[bb].w = fmaf(w3.w, h4.w, acc[bb].w);
                }
            }
            #pragma unroll
            for (int bb = 0; bb < NB; ++bb) {
                float2 hx = *(const float2*)(xbA + (bb << 4) + (ksub << 1));
                acc[bb].x = fmaf(Wv[16].x, hx.x, acc[bb].x);
                acc[bb].y = fmaf(Wv[16].y, hx.x, acc[bb].y);
                acc[bb].z = fmaf(Wv[16].z, hx.x, acc[bb].z);
                acc[bb].w = fmaf(Wv[16].w, hx.x, acc[bb].w);
                acc[bb].x = fmaf(Wv[17].x, hx.y, acc[bb].x);
                acc[bb].y = fmaf(Wv[17].y, hx.y, acc[bb].y);
                acc[bb].z = fmaf(Wv[17].z, hx.y, acc[bb].z);
                acc[bb].w = fmaf(Wv[17].w, hx.y, acc[bb].w);
            }
            #pragma unroll
            for (int bb = 0; bb < NB; ++bb) {
                acc[bb].x += __shfl_xor(acc[bb].x, 8);
                acc[bb].y += __shfl_xor(acc[bb].y, 8);
                acc[bb].z += __shfl_xor(acc[bb].z, 8);
                acc[bb].w += __shfl_xor(acc[bb].w, 8);
                acc[bb].x += __shfl_xor(acc[bb].x, 16);
                acc[bb].y += __shfl_xor(acc[bb].y, 16);
                acc[bb].z += __shfl_xor(acc[bb].z, 16);
                acc[bb].w += __shfl_xor(acc[bb].w, 16);
                acc[bb].x += __shfl_xor(acc[bb].x, 32);
                acc[bb].y += __shfl_xor(acc[bb].y, 32);
                acc[bb].z += __shfl_xor(acc[bb].z, 32);
                acc[bb].w += __shfl_xor(acc[bb].w, 32);
            }
            if (ksub == 0) {
                #pragma unroll
                for (int bb = 0; bb < NB; ++bb)
                    redA[((wave << 3) + jq) * 5 + bb] = acc[bb];
            }
        }
        __syncthreads();                               // redA(t) complete

        // issue chain B's step-t DMA LATE: epiB(t-1) publishers aged ~2.5us
        // (>= delta); flight overlaps epiA + B-consume entry.
        if (t > 0) {
            const float* pB = out + ((size_t)(t - 1) * BATCH + b0 + 4 + sbb) * HDIM
                              + krec + sko;
            issue_dma16(pB, hdB);
            issue_dma16(pB + 2 * HDIM, hdB + 256);
        }

        if (wave < 4 && lane < 8) {
            float4 s = make_float4(0.f, 0.f, 0.f, 0.f);
            #pragma unroll
            for (int w = 0; w < 8; ++w) {
                float4 r = redA[((w << 3) + lane) * 5 + wave];
                s.x += r.x; s.y += r.y; s.z += r.z; s.w += r.w;
            }
            float4 o;
            o.x = tanhf(s.x + b4.x);
            o.y = tanhf(s.y + b4.y);
            o.z = tanhf(s.z + b4.z);
            o.w = tanhf(s.w + b4.w);
            sc_store4_nodrain(out + ((size_t)t * BATCH + b0 + wave) * HDIM + jj, o);
            if (t == T_STEPS - 1)
                *(float4*)(hfin + (size_t)(b0 + wave) * HDIM + jj) = o;
        }

        // ================= chain B (rows b0+4..b0+7) =================
        *xdB = xvB;
        if (t == 0) {
            const float* p = h0 + (size_t)(b0 + 4 + sbb) * HDIM + krec + sko;
            *(float4*)(hdB)       = *(const float4*)(p);
            *(float4*)(hdB + 256) = *(const float4*)(p + 2 * HDIM);
        } else {
            wait_vmem0();
            float4 a = *(const float4*)(hdB);
            float4 b = *(const float4*)(hdB + 256);
            if (__any((int)(chk4(a) | chk4(b)))) {
                const float* p = out + ((size_t)(t - 1) * BATCH + b0 + 4 + sbb) * HDIM
                                 + krec + sko;
                do { sc_load2x4(p, p + 2 * HDIM, a, b); }
                while (__any((int)(chk4(a) | chk4(b))));
                *(float4*)(hdB)       = a;
                *(float4*)(hdB + 256) = b;
            }
        }
        if (t + 1 < T_STEPS)
            xvB = x[((size_t)(t + 1) * BATCH + b0 + 4 + xr) * IDIM
                    + (wave << 4) + xco];

        {
            float4 acc[NB];
            #pragma unroll
            for (int bb = 0; bb < NB; ++bb) acc[bb] = make_float4(0.f, 0.f, 0.f, 0.f);
            #pragma unroll
            for (int i = 0; i < 4; ++i) {
                const int ko = ((i << 3) + ksub) << 2;
                const float4 w0 = Wv[i * 4 + 0], w1 = Wv[i * 4 + 1];
                const float4 w2 = Wv[i * 4 + 2], w3 = Wv[i * 4 + 3];
                #pragma unroll
                for (int bb = 0; bb < NB; ++bb) {
                    float4 h4 = *(const float4*)(hbB + (bb << 7) + ko);
                    acc[bb].x = fmaf(w0.x, h4.x, acc[bb].x);
                    acc[bb].y = fmaf(w0.y, h4.x, acc[bb].y);
                    acc[bb].z = fmaf(w0.z, h4.x, acc[bb].z);
                    acc[bb].w = fmaf(w0.w, h4.x, acc[bb].w);
                    acc[bb].x = fmaf(w1.x, h4.y, acc[bb].x);
                    acc[bb].y = fmaf(w1.y, h4.y, acc[bb].y);
                    acc[bb].z = fmaf(w1.z, h4.y, acc[bb].z);
                    acc[bb].w = fmaf(w1.w, h4.y, acc[bb].w);
                    acc[bb].x = fmaf(w2.x, h4.z, acc[bb].x);
                    acc[bb].y = fmaf(w2.y, h4.z, acc[bb].y);
                    acc[bb].z = fmaf(w2.z, h4.z, acc[bb].z);
                    acc[bb].w = fmaf(w2.w, h4.z, acc[bb].w);
                    acc[bb].x = fmaf(w3.x, h4.w, acc[bb].x);
                    acc[bb].y = fmaf(w3.y, h4.w, acc[bb].y);
                    acc[bb].z = fmaf(w3.z, h4.w, acc[bb].z);
                    acc[bb].w = fmaf(w3.w, h4.w, acc[bb].w);
                }
            }
            #pragma unroll
            for (int bb = 0; bb < NB; ++bb) {
                float2 hx = *(const float2*)(xbB + (bb << 4) + (ksub << 1));
                acc[bb].x = fmaf(Wv[16].x, hx.x, acc[bb].x);
                acc[bb].y = fmaf(Wv[16].y, hx.x, acc[bb].y);
                acc[bb].z = fmaf(Wv[16].z, hx.x, acc[bb].z);
                acc[bb].w = fmaf(Wv[16].w, hx.x, acc[bb].w);
                acc[bb].x = fmaf(Wv[17].x, hx.y, acc[bb].x);
                acc[bb].y = fmaf(Wv[17].y, hx.y, acc[bb].y);
                acc[bb].z = fmaf(Wv[17].z, hx.y, acc[bb].z);
                acc[bb].w = fmaf(Wv[17].w, hx.y, acc[bb].w);
            }
            #pragma unroll
            for (int bb = 0; bb < NB; ++bb) {
                acc[bb].x += __shfl_xor(acc[bb].x, 8);
                acc[bb].y += __shfl_xor(acc[bb].y, 8);
                acc[bb].z += __shfl_xor(acc[bb].z, 8);
                acc[bb].w += __shfl_xor(acc[bb].w, 8);
                acc[bb].x += __shfl_xor(acc[bb].x, 16);
                acc[bb].y += __shfl_xor(acc[bb].y, 16);
                acc[bb].z += __shfl_xor(acc[bb].z, 16);
                acc[bb].w += __shfl_xor(acc[bb].w, 16);
                acc[bb].x += __shfl_xor(acc[bb].x, 32);
                acc[bb].y += __shfl_xor(acc[bb].y, 32);
                acc[bb].z += __shfl_xor(acc[bb].z, 32);
                acc[bb].w += __shfl_xor(acc[bb].w, 32);
            }
            if (ksub == 0) {
                #pragma unroll
                for (int bb = 0; bb < NB; ++bb)
                    redB[((wave << 3) + jq) * 5 + bb] = acc[bb];
            }
        }
        __syncthreads();                               // redB(t) complete

        // issue chain A's step-(t+1) DMA LATE: epiA(t) publishers aged ~2us;
        // flight overlaps epiB + next-period A-consume entry.
        if (t + 1 < T_STEPS) {
            const float* pA = out + ((size_t)t * BATCH + b0 + sbb) * HDIM
                              + krec + sko;
            issue_dma16(pA, hdA);
            issue_dma16(pA + 2 * HDIM, hdA + 256);
        }

        if (wave < 4 && lane < 8) {
            float4 s = make_float4(0.f, 0.f, 0.f, 0.f);
            #pragma unroll
            for (int w = 0; w < 8; ++w) {
                float4 r = redB[((w << 3) + lane) * 5 + wave];
                s.x += r.x; s.y += r.y; s.z += r.z; s.w += r.w;
            }
            float4 o;
            o.x = tanhf(s.x + b4.x);
            o.y = tanhf(s.y + b4.y);
            o.z = tanhf(s.z + b4.z);
            o.w = tanhf(s.w + b4.w);
            sc_store4_nodrain(out + ((size_t)t * BATCH + b0 + 4 + wave) * HDIM + jj, o);
            if (t == T_STEPS - 1)
                *(float4*)(hfin + (size_t)(b0 + 4 + wave) * HDIM + jj) = o;
        }
    }
}

extern "C" void kernel_launch(void* const* d_in, const int* in_sizes, int n_in,
                              void* d_out, int out_size, void* d_ws, size_t ws_size,
                              hipStream_t stream) {
    const float* x    = (const float*)d_in[0];
    const float* h0   = (const float*)d_in[1];
    const float* w_ih = (const float*)d_in[2];   // [1024][128]
    const float* w_hh = (const float*)d_in[3];   // [1024][1024]
    const float* bias = (const float*)d_in[4];   // [1024]
    float* out = (float*)d_out;

    char* ws = (char*)d_ws;
    float* WT = (float*)ws;                      // [1152][1024] = 4.72 MB

    // poison the polled region: byte 0x7F -> dword 0x7F7F7F7F = 3.4e38,
    // unreachable by tanh. Stream-ordered; re-arms on every replay.
    (void)hipMemsetAsync(out, 0x7F,
                         (size_t)T_STEPS * BATCH * HDIM * sizeof(float), stream);
    transpose_f32<<<256, 256, 0, stream>>>(w_hh, WT, HDIM, HDIM);
    transpose_f32<<<32, 256, 0, stream>>>(w_ih, WT + (size_t)HDIM * HDIM, HDIM, IDIM);
    esn_persistent<<<NWG, 512, 0, stream>>>(x, h0, WT, bias,
                                            out, out + (size_t)T_STEPS * BATCH * HDIM);
}